// Round 13
// baseline (5080.384 us; speedup 1.0000x reference)
//
#include <hip/hip_runtime.h>

// ConditionalSmilesRnn: 3-layer LSTM, B=256, H=1024, steps=99, V=47, P=3.
// R13: mega-dispatch v2. R10's proven counter-ordered dataflow (105 groups x
// 640 blocks; group d = {L0@d, xp1@d-1, L1@d-3, xp2@d-4, L2@d-6}) with fixed
// memory paths: weights CACHED (L2-resident across the whole dispatch -- no
// per-dispatch invalidation), h in FRESH 100-slot arrays read cached (first
// touch misses to L3, correct after producer's release-writeback), xp/c keep
// R10's exact proven store/load mechanics.

typedef unsigned short u16;
typedef __bf16 bf16x8 __attribute__((ext_vector_type(8)));
typedef float f32x4 __attribute__((ext_vector_type(4)));
typedef u16 u16x8 __attribute__((ext_vector_type(8)));

#define MFMA16(a,b,c) __builtin_amdgcn_mfma_f32_16x16x32_bf16((a),(b),(c),0,0,0)
#define BH 262144

__device__ __forceinline__ u16 f2bf(float f){
  unsigned u = __builtin_bit_cast(unsigned, f);
  u += 0x7fffu + ((u >> 16) & 1u);          // RN-even
  return (u16)(u >> 16);
}
__device__ __forceinline__ float bf2f(u16 s){
  unsigned u = ((unsigned)s) << 16;
  return __builtin_bit_cast(float, u);
}
__device__ __forceinline__ float sigm(float x){ return 1.f/(1.f+__expf(-x)); }
__device__ __forceinline__ float tanhfast(float x){ return 1.f - 2.f/(__expf(2.f*x)+1.f); }

__device__ __forceinline__ void ld_lds16(const u16* g, u16* l){
  __builtin_amdgcn_global_load_lds((const __attribute__((address_space(1))) void*)g,
                                   (__attribute__((address_space(3))) void*)l, 16, 0, 0);
}

__device__ __forceinline__ float xpload(const float* p){
  return __hip_atomic_load(p, __ATOMIC_RELAXED, __HIP_MEMORY_SCOPE_AGENT);
}

__device__ __forceinline__ void waitctr(const unsigned* c){
  if (threadIdx.x == 0){
    while (__hip_atomic_load(c, __ATOMIC_RELAXED, __HIP_MEMORY_SCOPE_AGENT) < 128u)
      __builtin_amdgcn_s_sleep(8);
  }
  __syncthreads();
  asm volatile("" ::: "memory");
}
__device__ __forceinline__ void donectr(unsigned* c){
  __syncthreads();
  if (threadIdx.x == 0)
    __hip_atomic_fetch_add(c, 1u, __ATOMIC_RELEASE, __HIP_MEMORY_SCOPE_AGENT);
}

// ---- f32 -> bf16 strided converter
__global__ void k_conv(const float* __restrict__ src, u16* __restrict__ dst,
                       long total, int srow, int sstride, int dstride, int doff){
  long i = ((long)blockIdx.x*blockDim.x + threadIdx.x)*8;
  if (i >= total) return;
  long r = i / srow;
  int  k = (int)(i - r*srow);
  const float* s = src + r*(long)sstride + k;
  u16x8 o;
  #pragma unroll
  for (int j=0;j<8;++j) o[j] = f2bf(s[j]);
  *(u16x8*)(dst + r*(long)dstride + doff + k) = o;
}

// ---- weight repack into per-(jt) contiguous stream blocks (K=1024, nkt=16).
__global__ void k_repackB(const float* __restrict__ Wih, const float* __restrict__ Whh,
                          u16* __restrict__ dst, int nkt){
  long p = (long)blockIdx.x*256 + threadIdx.x;
  int G = (int)(p & 511);
  long q = p >> 9;
  int kt = (int)(q % nkt);
  int jt = (int)(q / nkt);
  int r = G >> 3, s = G & 7;
  int kk = kt*64 + ((s ^ (r & 7)) << 3);
  int n = (r >> 4)*1024 + jt*16 + (r & 15);
  const float* src = (kk < 1024) ? Wih + (size_t)n*1024 + kk
                                 : Whh + (size_t)n*1024 + (kk - 1024);
  u16x8 o;
  #pragma unroll
  for (int j=0;j<8;++j) o[j] = f2bf(src[j]);
  *(u16x8*)(dst + p*8) = o;
}

// ---- misc prep: biases, pad rows, state init (slot 0), gx_prop, counters=0
__global__ void k_misc(const float* __restrict__ b_ih0, const float* __restrict__ b_hh0,
                       const float* __restrict__ b_ihr, const float* __restrict__ b_hhr,
                       const float* __restrict__ h0, const float* __restrict__ c0,
                       const float* __restrict__ props, const float* __restrict__ W_ih0,
                       u16* __restrict__ Ebf, u16* __restrict__ Wdec,
                       float* __restrict__ bias0, float* __restrict__ bcat,
                       u16* __restrict__ hist0, u16* __restrict__ hist1,
                       u16* __restrict__ outsbF,
                       float* __restrict__ cst, float* __restrict__ gxp,
                       unsigned* __restrict__ ctrs){
  long i = (long)blockIdx.x*256 + threadIdx.x;
  if (i < 4096){ bias0[i] = b_ih0[i] + b_hh0[i]; return; }
  i -= 4096;
  if (i < 2*4096){ bcat[i] = b_ihr[i] + b_hhr[i]; return; }
  i -= 2*4096;
  if (i < 1024){ Ebf[47*1024 + i] = 0; Wdec[47*1024 + i] = 0; return; }
  i -= 1024;
  if (i < (long)3*BH){
    int l = (int)(i >> 18); long r = i & (BH-1);
    u16 v = f2bf(h0[i]);
    if (l==0)      hist0[r] = v;          // slot 0 = init
    else if (l==1) hist1[r] = v;
    else           outsbF[r] = v;
    cst[i] = c0[i];
    return;
  }
  i -= (long)3*BH;
  if (i < (long)256*4096){
    int b = (int)(i >> 12), n = (int)(i & 4095);
    const float* wr = W_ih0 + (long)n*1027 + 1024;
    gxp[i] = props[b*3+0]*wr[0] + props[b*3+1]*wr[1] + props[b*3+2]*wr[2];
    return;
  }
  i -= (long)256*4096;
  if (i < 1024) ctrs[i] = 0;
}

// ---- gx_emb[v][n] = sum_k E[v][k] * W_ih0[n][k]  (M=48 padded, N=4096, K=1024)
__global__ __launch_bounds__(64)
void k_gxemb(const u16* __restrict__ Ebf, const u16* __restrict__ Wih0b, float* __restrict__ gxe){
  const int lane = threadIdx.x;
  const int cl = lane & 15, ko = (lane >> 4)*8;
  const int m0 = blockIdx.x*16;
  const int n0 = blockIdx.y*16;
  f32x4 acc = {0.f,0.f,0.f,0.f};
  const u16* ap = Ebf   + (size_t)(m0+cl)*1024 + ko;
  const u16* bp = Wih0b + (size_t)(n0+cl)*1024 + ko;
  for (int k0=0; k0<1024; k0+=32){
    bf16x8 a = *(const bf16x8*)(ap + k0);
    bf16x8 b = *(const bf16x8*)(bp + k0);
    acc = MFMA16(a, b, acc);
  }
  const int rbase = (lane >> 4)*4;
  #pragma unroll
  for (int q=0;q<4;++q){
    int v = m0 + rbase + q;
    if (v < 47) gxe[(size_t)v*4096 + n0 + cl] = acc[q];
  }
}

// ================= shared K-loop (TM=128 x TN=64, K=1024, NT=16) =================
// 3 LDS slots x 24KB, 2-deep prefetch, one barrier per chunk, counted vmcnt.
// A and B both CACHED (aux=0): weights L2-resident in-dispatch; h fresh addrs.
#define KLOOP_BODY(APTR_EXPR)                                                   \
  auto stage = [&](int s, int kt){                                              \
    const int kbase = kt*64;                                                    \
    u16* sA = lds + (size_t)s*12288;                                            \
    u16* sB = sA + 8192;                                                        \
    _Pragma("unroll")                                                           \
    for (int j=0;j<4;++j){                                                      \
      int G = j*256 + tid; int r = G >> 3;                                      \
      int kk = kbase + (((G & 7) ^ (r & 7)) << 3);                              \
      ld_lds16(APTR_EXPR, sA + (size_t)G*8);                                    \
    }                                                                           \
    _Pragma("unroll")                                                           \
    for (int j=0;j<2;++j){                                                      \
      int G = j*256 + tid;                                                      \
      ld_lds16(Bblk + (size_t)kt*4096 + (size_t)G*8, sB + (size_t)G*8);         \
    }                                                                           \
  };                                                                            \
  f32x4 acc[2][4];                                                              \
  _Pragma("unroll")                                                             \
  for (int mf=0; mf<2; ++mf)                                                    \
    _Pragma("unroll")                                                           \
    for (int g=0; g<4; ++g) acc[mf][g] = (f32x4){0.f,0.f,0.f,0.f};              \
  stage(0,0); stage(1,1);                                                       \
  for (int kt=0; kt<16; ++kt){                                                  \
    if (kt == 15) asm volatile("s_waitcnt vmcnt(0)" ::: "memory");              \
    else          asm volatile("s_waitcnt vmcnt(6)" ::: "memory");              \
    __builtin_amdgcn_s_barrier();                                               \
    asm volatile("" ::: "memory");                                              \
    if (kt+2 < 16) stage((kt+2)%3, kt+2);                                       \
    const u16* A = lds + (size_t)(kt%3)*12288;                                  \
    const u16* B = A + 8192;                                                    \
    __builtin_amdgcn_s_setprio(1);                                              \
    _Pragma("unroll")                                                           \
    for (int half=0; half<2; ++half){                                           \
      const int kg = half*4 + hi;                                               \
      bf16x8 a0, a1, b[4];                                                      \
      { int r = m0w + cl;      a0 = *(const bf16x8*)(A + r*64 + ((kg ^ (r&7))<<3)); } \
      { int r = m0w + 16 + cl; a1 = *(const bf16x8*)(A + r*64 + ((kg ^ (r&7))<<3)); } \
      _Pragma("unroll")                                                         \
      for (int g=0; g<4; ++g){                                                  \
        int r = g*16 + cl;                                                      \
        b[g] = *(const bf16x8*)(B + r*64 + ((kg ^ (r&7))<<3));                  \
      }                                                                         \
      _Pragma("unroll")                                                         \
      for (int g=0; g<4; ++g){                                                  \
        acc[0][g] = MFMA16(a0, b[g], acc[0][g]);                                \
        acc[1][g] = MFMA16(a1, b[g], acc[1][g]);                                \
      }                                                                         \
    }                                                                           \
    __builtin_amdgcn_s_setprio(0);                                              \
    asm volatile("" ::: "memory");                                              \
  }

// ---- diag tile: gates = W_hh . h_prev (+ gxe/gxp or xpart) + bias; fused cell.
template<int LAYER>
__device__ __forceinline__ void diagh_tile(int mt, int jt, int t,
    const int* __restrict__ x, const u16* hp, u16* aux, float* cc,
    const u16* __restrict__ Bblk, const float* __restrict__ bias,
    const float* __restrict__ gxe, const float* __restrict__ gxp,
    const float* xpt, u16* lds)
{
  const int tid = threadIdx.x;
  const int lane = tid & 63, w = tid >> 6;
  const int cl = lane & 15, hi = lane >> 4;
  const int m_base = mt*128, m0w = w*32;

  KLOOP_BODY(hp + (size_t)(m_base + r)*1024 + kk)

  // fused LSTM cell. C/D: col = cl (-> hcol), row = hi*4+q (-> batch)
  volatile float* cv = cc;
  const int hcol = jt*16 + cl;
  const float bi_ = bias[hcol], bf_ = bias[1024+hcol],
              bg_ = bias[2048+hcol], bo_ = bias[3072+hcol];
  #pragma unroll
  for (int mf=0; mf<2; ++mf){
    #pragma unroll
    for (int q=0; q<4; ++q){
      const int row = m_base + m0w + mf*16 + hi*4 + q;
      float gi = acc[mf][0][q] + bi_;
      float gf = acc[mf][1][q] + bf_;
      float gg = acc[mf][2][q] + bg_;
      float go = acc[mf][3][q] + bo_;
      if (LAYER == 0){
        const int tok = (t==0) ? 1 : x[row*100 + t];
        const float* ge = gxe + (size_t)tok*4096;
        const float* gp = gxp + (size_t)row*4096;
        gi += ge[hcol]        + gp[hcol];
        gf += ge[1024 + hcol] + gp[1024 + hcol];
        gg += ge[2048 + hcol] + gp[2048 + hcol];
        go += ge[3072 + hcol] + gp[3072 + hcol];
      } else {
        const float* xr = xpt + (size_t)row*4096;
        gi += xpload(xr + hcol);
        gf += xpload(xr + 1024 + hcol);
        gg += xpload(xr + 2048 + hcol);
        go += xpload(xr + 3072 + hcol);
      }
      const float i_ = sigm(gi), f_ = sigm(gf), o_ = sigm(go), g_ = tanhfast(gg);
      const size_t off = (size_t)row*1024 + hcol;
      const float cn = f_*cv[off] + i_*g_;
      cv[off] = cn;
      aux[off] = f2bf(o_*tanhfast(cn));
    }
  }
}

// ---- xp tile: xpart rows [m_base, m_base+128) of one step -> f32
__device__ __forceinline__ void xp_tile(int m_base, int jt,
    const u16* hp, const u16* __restrict__ Bblk, float* xpo, u16* lds)
{
  const int tid = threadIdx.x;
  const int lane = tid & 63, w = tid >> 6;
  const int cl = lane & 15, hi = lane >> 4;
  const int m0w = w*32;

  KLOOP_BODY(hp + (size_t)(m_base + r)*1024 + kk)

  const int hcol = jt*16 + cl;
  #pragma unroll
  for (int mf=0; mf<2; ++mf){
    #pragma unroll
    for (int q=0; q<4; ++q){
      const int m = m_base + m0w + mf*16 + hi*4 + q;
      float* xr = xpo + (size_t)m*4096 + hcol;
      xr[0]    = acc[mf][0][q];
      xr[1024] = acc[mf][1][q];
      xr[2048] = acc[mf][2][q];
      xr[3072] = acc[mf][3][q];
    }
  }
}

// ---- the mega dispatch: gid = d*640 + slot; stage = slot>>7.
// group d = {L0@d, xp1@d-1, L1@d-3, xp2@d-4, L2@d-6}.
// h slot convention: array slot (t+1) holds h@t; slot 0 = init.
__global__ __launch_bounds__(256)
void k_mega(const int* __restrict__ x, u16* hist0, u16* hist1, u16* outsbF,
            float* __restrict__ cst, const u16* __restrict__ WpkH,
            const u16* __restrict__ WpkI,
            const float* __restrict__ bias0, const float* __restrict__ bcat,
            const float* __restrict__ gxe, const float* __restrict__ gxp,
            float* __restrict__ xpb1, float* __restrict__ xpb2,
            unsigned* __restrict__ ctrs)
{
  extern __shared__ u16 lds[];
  const int gid = blockIdx.x;
  const int d = gid / 640;
  const int slot = gid - d*640;
  const int stg = slot >> 7;
  const int loc = slot & 127;
  const int mt = loc >> 6, jt = loc & 63;
  unsigned* ctr0  = ctrs;
  unsigned* ctrX1 = ctrs + 128;
  unsigned* ctr1  = ctrs + 256;
  unsigned* ctrX2 = ctrs + 384;
  unsigned* ctr2  = ctrs + 512;

  if (stg == 0){                              // L0 @ t=d
    const int t = d; if (t > 98) return;
    if (t > 0) waitctr(ctr0 + (t-1));
    diagh_tile<0>(mt, jt, t, x, hist0 + (size_t)t*BH, hist0 + (size_t)(t+1)*BH,
                  cst, WpkH + (size_t)jt*65536, bias0, gxe, gxp, nullptr, lds);
    donectr(ctr0 + t);
  } else if (stg == 1){                       // xp1(t) = Wih1 . h0[t], t=d-1
    const int t = d - 1; if (t < 0 || t > 98) return;
    waitctr(ctr0 + t);
    if (t >= 4) waitctr(ctr1 + (t-4));        // ring slot's previous reader done
    xp_tile(mt*128, jt, hist0 + (size_t)(t+1)*BH, WpkI + (size_t)jt*65536,
            xpb1 + (size_t)(t&3)*1048576, lds);
    donectr(ctrX1 + t);
  } else if (stg == 2){                       // L1 @ t=d-3
    const int t = d - 3; if (t < 0 || t > 98) return;
    waitctr(ctrX1 + t);
    if (t > 0) waitctr(ctr1 + (t-1));
    diagh_tile<1>(mt, jt, t, x, hist1 + (size_t)t*BH, hist1 + (size_t)(t+1)*BH,
                  cst + BH, WpkH + (size_t)4194304 + (size_t)jt*65536, bcat,
                  nullptr, nullptr, xpb1 + (size_t)(t&3)*1048576, lds);
    donectr(ctr1 + t);
  } else if (stg == 3){                       // xp2(t) = Wih2 . h1[t], t=d-4
    const int t = d - 4; if (t < 0 || t > 98) return;
    waitctr(ctr1 + t);
    if (t >= 4) waitctr(ctr2 + (t-4));
    xp_tile(mt*128, jt, hist1 + (size_t)(t+1)*BH, WpkI + (size_t)4194304 + (size_t)jt*65536,
            xpb2 + (size_t)(t&3)*1048576, lds);
    donectr(ctrX2 + t);
  } else {                                    // L2 @ t=d-6
    const int t = d - 6; if (t < 0 || t > 98) return;
    waitctr(ctrX2 + t);
    if (t > 0) waitctr(ctr2 + (t-1));
    diagh_tile<2>(mt, jt, t, x, outsbF + (size_t)t*BH, outsbF + (size_t)(t+1)*BH,
                  cst + 2*BH, WpkH + (size_t)8388608 + (size_t)jt*65536, bcat + 4096,
                  nullptr, nullptr, xpb2 + (size_t)(t&3)*1048576, lds);
    donectr(ctr2 + t);
  }
}

// ---- decoder: logits[b,t,v] = outs[t,b,:] . Wdec[v,:] + b_dec[v]
__global__ __launch_bounds__(256)
void k_decode(const u16* __restrict__ outs, const u16* __restrict__ Wdec,
              const float* __restrict__ bdec, float* __restrict__ logits){
  const int lane = threadIdx.x & 63, w = threadIdx.x >> 6;
  const int cl = lane & 15, ko = (lane >> 4)*8;
  const size_t m0 = ((size_t)blockIdx.x*4 + w)*16;
  const u16* ap = outs + (m0+cl)*1024 + ko;
  f32x4 acc[3];
  #pragma unroll
  for (int nt=0; nt<3; ++nt) acc[nt] = (f32x4){0.f,0.f,0.f,0.f};
  const u16* bp = Wdec + (size_t)cl*1024 + ko;
  for (int k0=0; k0<1024; k0+=32){
    bf16x8 a = *(const bf16x8*)(ap + k0);
    #pragma unroll
    for (int nt=0; nt<3; ++nt){
      bf16x8 b = *(const bf16x8*)(bp + (size_t)nt*16*1024 + k0);
      acc[nt] = MFMA16(a, b, acc[nt]);
    }
  }
  const int rbase = (lane >> 4)*4;
  #pragma unroll
  for (int nt=0; nt<3; ++nt){
    #pragma unroll
    for (int q=0; q<4; ++q){
      int v = nt*16 + cl;
      if (v < 47){
        size_t row = m0 + rbase + q;   // row = t*256 + b
        int tt = (int)(row >> 8);
        int b  = (int)(row & 255);
        logits[((size_t)b*99 + tt)*47 + v] = acc[nt][q] + bdec[v];
      }
    }
  }
}

// ---- final hT / cT copy-out (h@98 = slot 99)
__global__ void k_final(const u16* __restrict__ h0s, const u16* __restrict__ h1s,
                        const u16* __restrict__ h2s, const float* __restrict__ cst,
                        float* __restrict__ out){
  long i = (long)blockIdx.x*256 + threadIdx.x;
  if (i < (long)3*BH){
    int l = (int)(i >> 18); long r = i & (BH-1);
    const u16* src = (l==0) ? h0s : (l==1) ? h1s : h2s;
    out[1191168 + i] = bf2f(src[r]);
    out[1191168 + 786432 + i] = cst[i];
  }
}

extern "C" void kernel_launch(void* const* d_in, const int* in_sizes, int n_in,
                              void* d_out, int out_size, void* d_ws, size_t ws_size,
                              hipStream_t stream) {
  (void)in_sizes; (void)n_in; (void)out_size; (void)ws_size;
  const int*   x      = (const int*)  d_in[0];
  const float* props  = (const float*)d_in[1];
  const float* h0     = (const float*)d_in[2];
  const float* c0     = (const float*)d_in[3];
  const float* E      = (const float*)d_in[4];
  const float* W_ih0  = (const float*)d_in[5];
  const float* W_hh0  = (const float*)d_in[6];
  const float* b_ih0  = (const float*)d_in[7];
  const float* b_hh0  = (const float*)d_in[8];
  const float* W_ih_r = (const float*)d_in[9];
  const float* W_hh_r = (const float*)d_in[10];
  const float* b_ih_r = (const float*)d_in[11];
  const float* b_hh_r = (const float*)d_in[12];
  const float* W_dec  = (const float*)d_in[13];
  const float* b_dec  = (const float*)d_in[14];
  float* out = (float*)d_out;

  // workspace layout (~235 MB)
  u16* WpkH   = (u16*)d_ws;                 // 3 x 4,194,304 (W_hh stream blocks)
  u16* WpkI   = WpkH  + (size_t)12582912;   // 2 x 4,194,304 (W_ih_r stream blocks)
  u16* Wdec   = WpkI  + (size_t)8388608;    // 48*1024 (row 47 = 0)
  u16* Ebf    = Wdec  + (size_t)49152;      // 48*1024 (row 47 = 0)
  u16* hist0  = Ebf   + (size_t)49152;      // 100 x BH (slot t+1 = h0@t; slot 0 init)
  u16* hist1  = hist0 + (size_t)100*BH;     // 100 x BH
  u16* outsbF = hist1 + (size_t)100*BH;     // 100 x BH (slot t+1 = h2@t; slot 0 init)
  float* xpb1 = (float*)(outsbF + (size_t)100*BH); // [4 slots][256][4096] f32
  float* xpb2 = xpb1  + (size_t)4194304;           // same
  u16* Wih0b  = (u16*)xpb1;                 // ALIAS: prep-only, dead before xp writes
  float* gxe   = xpb2  + (size_t)4194304;          // 48*4096
  float* gxp   = gxe   + (size_t)196608;           // 256*4096
  float* bias0 = gxp   + (size_t)1048576;          // 4096
  float* bcat  = bias0 + 4096;                     // 2*4096
  float* cst   = bcat  + 8192;                     // 3 x BH f32
  unsigned* ctrs = (unsigned*)(cst + (size_t)3*BH); // 1024 (5 x 99 used)

  // ---- prep
  k_repackB<<<2048, 256, 0, stream>>>(W_hh0, W_hh0, WpkH, 16);
  k_repackB<<<2048, 256, 0, stream>>>(W_hh_r, W_hh_r, WpkH + (size_t)4194304, 16);
  k_repackB<<<2048, 256, 0, stream>>>(W_hh_r + (size_t)4194304, W_hh_r + (size_t)4194304,
                                      WpkH + (size_t)8388608, 16);
  k_repackB<<<2048, 256, 0, stream>>>(W_ih_r, W_ih_r, WpkI, 16);
  k_repackB<<<2048, 256, 0, stream>>>(W_ih_r + (size_t)4194304, W_ih_r + (size_t)4194304,
                                      WpkI + (size_t)4194304, 16);
  k_conv<<<2048, 256, 0, stream>>>(W_ih0, Wih0b, (long)4096*1024, 1024, 1027, 1024, 0);
  k_conv<<<24,   256, 0, stream>>>(E,     Ebf,   (long)47*1024,   1024, 1024, 1024, 0);
  k_conv<<<24,   256, 0, stream>>>(W_dec, Wdec,  (long)47*1024,   1024, 1024, 1024, 0);
  k_misc<<<7224, 256, 0, stream>>>(b_ih0, b_hh0, b_ih_r, b_hh_r, h0, c0, props, W_ih0,
                                   Ebf, Wdec, bias0, bcat, hist0, hist1, outsbF, cst,
                                   gxp, ctrs);
  k_gxemb<<<dim3(3,256), 64, 0, stream>>>(Ebf, Wih0b, gxe);

  // ---- mega recurrence: one dispatch, 105 groups x 640 blocks, flag-ordered
  (void)hipFuncSetAttribute(reinterpret_cast<const void*>(k_mega),
                            hipFuncAttributeMaxDynamicSharedMemorySize, 73728);
  k_mega<<<67200, 256, 73728, stream>>>(x, hist0, hist1, outsbF, cst, WpkH, WpkI,
                                        bias0, bcat, gxe, gxp, xpb1, xpb2, ctrs);

  // ---- decode + final states
  k_decode<<<396, 256, 0, stream>>>(outsbF + (size_t)BH, Wdec, b_dec, out);
  k_final<<<3072, 256, 0, stream>>>(hist0 + (size_t)99*BH, hist1 + (size_t)99*BH,
                                    outsbF + (size_t)99*BH, cst, out);
}

// Round 14
// 2747.049 us; speedup vs baseline: 1.8494x; 1.8494x over previous
//
#include <hip/hip_runtime.h>

// ConditionalSmilesRnn: 3-layer LSTM, B=256, H=1024, steps=99, V=47, P=3.
// R14: R9 structure (merged diag+xp dispatches) + (1) in-loop weight pretouch
// (2-chunk lead over stage, exact vmcnt ladder), (2) window-4 xp batches
// (skews {0,5,10}; xp1 at d%4==0, xp2 at d%4==1; halves W_ih refetch),
// (3) gxe/gxp stored bf16 (-2.5MB/step on L0).

typedef unsigned short u16;
typedef __bf16 bf16x8 __attribute__((ext_vector_type(8)));
typedef float f32x4 __attribute__((ext_vector_type(4)));
typedef u16 u16x8 __attribute__((ext_vector_type(8)));

#define MFMA16(a,b,c) __builtin_amdgcn_mfma_f32_16x16x32_bf16((a),(b),(c),0,0,0)
#define BH 262144

__device__ __forceinline__ u16 f2bf(float f){
  unsigned u = __builtin_bit_cast(unsigned, f);
  u += 0x7fffu + ((u >> 16) & 1u);          // RN-even
  return (u16)(u >> 16);
}
__device__ __forceinline__ float bf2f(u16 s){
  unsigned u = ((unsigned)s) << 16;
  return __builtin_bit_cast(float, u);
}
__device__ __forceinline__ float sigm(float x){ return 1.f/(1.f+__expf(-x)); }
__device__ __forceinline__ float tanhfast(float x){ return 1.f - 2.f/(__expf(2.f*x)+1.f); }

__device__ __forceinline__ void ld_lds16(const u16* g, u16* l){
  __builtin_amdgcn_global_load_lds((const __attribute__((address_space(1))) void*)g,
                                   (__attribute__((address_space(3))) void*)l, 16, 0, 0);
}

// ---- f32 -> bf16 strided converter
__global__ void k_conv(const float* __restrict__ src, u16* __restrict__ dst,
                       long total, int srow, int sstride, int dstride, int doff){
  long i = ((long)blockIdx.x*blockDim.x + threadIdx.x)*8;
  if (i >= total) return;
  long r = i / srow;
  int  k = (int)(i - r*srow);
  const float* s = src + r*(long)sstride + k;
  u16x8 o;
  #pragma unroll
  for (int j=0;j<8;++j) o[j] = f2bf(s[j]);
  *(u16x8*)(dst + r*(long)dstride + doff + k) = o;
}

// ---- weight repack into per-(jt) contiguous stream blocks (K=1024, nkt=16).
__global__ void k_repackB(const float* __restrict__ Wih, const float* __restrict__ Whh,
                          u16* __restrict__ dst, int nkt){
  long p = (long)blockIdx.x*256 + threadIdx.x;
  int G = (int)(p & 511);
  long q = p >> 9;
  int kt = (int)(q % nkt);
  int jt = (int)(q / nkt);
  int r = G >> 3, s = G & 7;
  int kk = kt*64 + ((s ^ (r & 7)) << 3);
  int n = (r >> 4)*1024 + jt*16 + (r & 15);
  const float* src = (kk < 1024) ? Wih + (size_t)n*1024 + kk
                                 : Whh + (size_t)n*1024 + (kk - 1024);
  u16x8 o;
  #pragma unroll
  for (int j=0;j<8;++j) o[j] = f2bf(src[j]);
  *(u16x8*)(dst + p*8) = o;
}

// ---- misc prep: biases, pad-row zeroing, state init (hist rings), gx_prop(bf16)
__global__ void k_misc(const float* __restrict__ b_ih0, const float* __restrict__ b_hh0,
                       const float* __restrict__ b_ihr, const float* __restrict__ b_hhr,
                       const float* __restrict__ h0, const float* __restrict__ c0,
                       const float* __restrict__ props, const float* __restrict__ W_ih0,
                       u16* __restrict__ Ebf, u16* __restrict__ Wdec,
                       float* __restrict__ bias0, float* __restrict__ bcat,
                       u16* __restrict__ hist0, u16* __restrict__ hist1,
                       u16* __restrict__ outsbF,
                       float* __restrict__ cst, u16* __restrict__ gxp){
  long i = (long)blockIdx.x*256 + threadIdx.x;
  if (i < 4096){ bias0[i] = b_ih0[i] + b_hh0[i]; return; }
  i -= 4096;
  if (i < 2*4096){ bcat[i] = b_ihr[i] + b_hhr[i]; return; }
  i -= 2*4096;
  if (i < 1024){ Ebf[47*1024 + i] = 0; Wdec[47*1024 + i] = 0; return; }
  i -= 1024;
  if (i < (long)3*BH){
    int l = (int)(i >> 18); long r = i & (BH-1);
    u16 v = f2bf(h0[i]);
    if (l==0)      hist0[(size_t)7*BH + r] = v;
    else if (l==1) hist1[(size_t)7*BH + r] = v;
    else           outsbF[r] = v;
    cst[i] = c0[i];
    return;
  }
  i -= (long)3*BH;
  if (i < (long)256*4096){
    int b = (int)(i >> 12), n = (int)(i & 4095);
    const float* wr = W_ih0 + (long)n*1027 + 1024;
    gxp[i] = f2bf(props[b*3+0]*wr[0] + props[b*3+1]*wr[1] + props[b*3+2]*wr[2]);
  }
}

// ---- gx_emb[v][n] = sum_k E[v][k] * W_ih0[n][k] -> bf16
__global__ __launch_bounds__(64)
void k_gxemb(const u16* __restrict__ Ebf, const u16* __restrict__ Wih0b, u16* __restrict__ gxe){
  const int lane = threadIdx.x;
  const int cl = lane & 15, ko = (lane >> 4)*8;
  const int m0 = blockIdx.x*16;
  const int n0 = blockIdx.y*16;
  f32x4 acc = {0.f,0.f,0.f,0.f};
  const u16* ap = Ebf   + (size_t)(m0+cl)*1024 + ko;
  const u16* bp = Wih0b + (size_t)(n0+cl)*1024 + ko;
  for (int k0=0; k0<1024; k0+=32){
    bf16x8 a = *(const bf16x8*)(ap + k0);
    bf16x8 b = *(const bf16x8*)(bp + k0);
    acc = MFMA16(a, b, acc);
  }
  const int rbase = (lane >> 4)*4;
  #pragma unroll
  for (int q=0;q<4;++q){
    int v = m0 + rbase + q;
    if (v < 47) gxe[(size_t)v*4096 + n0 + cl] = f2bf(acc[q]);
  }
}

// ================= shared K-loop (TM=128 x TN=64, K=1024, NT=16) =================
// 3 LDS slots x 24KB + 1KB trash, 2-deep stage prefetch, in-loop B pretouch
// (chunk kt+4 -> trash LDS; fills L2 2 chunks early). vmcnt ladder derived for
// issue order [S(kt+2):6, P(kt+4):2]: need S(kt) retired ->
// newer = P(kt+2)+S(kt+1)+P(kt+3): kt=0:6, 1:8, 2..12:10, 13:8, 14:6, 15:0.
#define KLOOP_BODY(APTR_EXPR)                                                   \
  u16* const trash = lds + 36864;                                               \
  auto stage = [&](int s, int kt){                                              \
    const int kbase = kt*64;                                                    \
    u16* sA = lds + (size_t)s*12288;                                            \
    u16* sB = sA + 8192;                                                        \
    _Pragma("unroll")                                                           \
    for (int j=0;j<4;++j){                                                      \
      int G = j*256 + tid; int r = G >> 3;                                      \
      int kk = kbase + (((G & 7) ^ (r & 7)) << 3);                              \
      ld_lds16(APTR_EXPR, sA + (size_t)G*8);                                    \
    }                                                                           \
    _Pragma("unroll")                                                           \
    for (int j=0;j<2;++j){                                                      \
      int G = j*256 + tid;                                                      \
      ld_lds16(Bblk + (size_t)kt*4096 + (size_t)G*8, sB + (size_t)G*8);         \
    }                                                                           \
  };                                                                            \
  auto pret = [&](int kt){                                                      \
    _Pragma("unroll")                                                           \
    for (int j=0;j<2;++j){                                                      \
      int G = j*256 + tid;                                                      \
      ld_lds16(Bblk + (size_t)kt*4096 + (size_t)G*8, trash);                    \
    }                                                                           \
  };                                                                            \
  f32x4 acc[2][4];                                                              \
  _Pragma("unroll")                                                             \
  for (int mf=0; mf<2; ++mf)                                                    \
    _Pragma("unroll")                                                           \
    for (int g=0; g<4; ++g) acc[mf][g] = (f32x4){0.f,0.f,0.f,0.f};              \
  stage(0,0); stage(1,1);                                                       \
  for (int kt=0; kt<16; ++kt){                                                  \
    if (kt == 0)       asm volatile("s_waitcnt vmcnt(6)"  ::: "memory");        \
    else if (kt == 1)  asm volatile("s_waitcnt vmcnt(8)"  ::: "memory");        \
    else if (kt <= 12) asm volatile("s_waitcnt vmcnt(10)" ::: "memory");        \
    else if (kt == 13) asm volatile("s_waitcnt vmcnt(8)"  ::: "memory");        \
    else if (kt == 14) asm volatile("s_waitcnt vmcnt(6)"  ::: "memory");        \
    else               asm volatile("s_waitcnt vmcnt(0)"  ::: "memory");        \
    __builtin_amdgcn_s_barrier();                                               \
    asm volatile("" ::: "memory");                                              \
    if (kt+2 < 16) stage((kt+2)%3, kt+2);                                       \
    if (kt+4 < 16) pret(kt+4);                                                  \
    const u16* A = lds + (size_t)(kt%3)*12288;                                  \
    const u16* B = A + 8192;                                                    \
    __builtin_amdgcn_s_setprio(1);                                              \
    _Pragma("unroll")                                                           \
    for (int half=0; half<2; ++half){                                           \
      const int kg = half*4 + hi;                                               \
      bf16x8 a0, a1, b[4];                                                      \
      { int r = m0w + cl;      a0 = *(const bf16x8*)(A + r*64 + ((kg ^ (r&7))<<3)); } \
      { int r = m0w + 16 + cl; a1 = *(const bf16x8*)(A + r*64 + ((kg ^ (r&7))<<3)); } \
      _Pragma("unroll")                                                         \
      for (int g=0; g<4; ++g){                                                  \
        int r = g*16 + cl;                                                      \
        b[g] = *(const bf16x8*)(B + r*64 + ((kg ^ (r&7))<<3));                  \
      }                                                                         \
      _Pragma("unroll")                                                         \
      for (int g=0; g<4; ++g){                                                  \
        acc[0][g] = MFMA16(a0, b[g], acc[0][g]);                                \
        acc[1][g] = MFMA16(a1, b[g], acc[1][g]);                                \
      }                                                                         \
    }                                                                           \
    __builtin_amdgcn_s_setprio(0);                                              \
    asm volatile("" ::: "memory");                                              \
  }

// ---- diag tile: gates = W_hh . h_prev (+ gxe/gxp or xpart) + bias; fused cell.
template<int LAYER>
__device__ __forceinline__ void diagh_tile(int mt, int jt, int t,
    const int* __restrict__ x, const u16* hp, u16* aux, float* cc,
    const u16* __restrict__ Bblk, const float* __restrict__ bias,
    const u16* __restrict__ gxe, const u16* __restrict__ gxp,
    const u16* xpt, u16* lds)
{
  const int tid = threadIdx.x;
  const int lane = tid & 63, w = tid >> 6;
  const int cl = lane & 15, hi = lane >> 4;
  const int m_base = mt*128, m0w = w*32;

  KLOOP_BODY(hp + (size_t)(m_base + r)*1024 + kk)

  // fused LSTM cell. C/D: col = cl (-> hcol), row = hi*4+q (-> batch)
  const int hcol = jt*16 + cl;
  const float bi_ = bias[hcol], bf_ = bias[1024+hcol],
              bg_ = bias[2048+hcol], bo_ = bias[3072+hcol];
  #pragma unroll
  for (int mf=0; mf<2; ++mf){
    #pragma unroll
    for (int q=0; q<4; ++q){
      const int row = m_base + m0w + mf*16 + hi*4 + q;
      float gi = acc[mf][0][q] + bi_;
      float gf = acc[mf][1][q] + bf_;
      float gg = acc[mf][2][q] + bg_;
      float go = acc[mf][3][q] + bo_;
      if (LAYER == 0){
        const int tok = (t==0) ? 1 : x[row*100 + t];
        const u16* ge = gxe + (size_t)tok*4096;
        const u16* gp = gxp + (size_t)row*4096;
        gi += bf2f(ge[hcol])        + bf2f(gp[hcol]);
        gf += bf2f(ge[1024 + hcol]) + bf2f(gp[1024 + hcol]);
        gg += bf2f(ge[2048 + hcol]) + bf2f(gp[2048 + hcol]);
        go += bf2f(ge[3072 + hcol]) + bf2f(gp[3072 + hcol]);
      } else {
        const u16* xr = xpt + (size_t)row*4096;
        gi += bf2f(xr[hcol]);
        gf += bf2f(xr[1024 + hcol]);
        gg += bf2f(xr[2048 + hcol]);
        go += bf2f(xr[3072 + hcol]);
      }
      const float i_ = sigm(gi), f_ = sigm(gf), o_ = sigm(go), g_ = tanhfast(gg);
      const size_t off = (size_t)row*1024 + hcol;
      const float cn = f_*cc[off] + i_*g_;
      cc[off] = cn;
      aux[off] = f2bf(o_*tanhfast(cn));
    }
  }
}

// ---- xp tile: xpart rows [m_base, m_base+128) of one step t -> bf16
__device__ __forceinline__ void xp_tile(int m_base, int jt,
    const u16* hp, const u16* __restrict__ Bblk, u16* xpo, u16* lds)
{
  const int tid = threadIdx.x;
  const int lane = tid & 63, w = tid >> 6;
  const int cl = lane & 15, hi = lane >> 4;
  const int m0w = w*32;

  KLOOP_BODY(hp + (size_t)(m_base + r)*1024 + kk)

  const int hcol = jt*16 + cl;
  #pragma unroll
  for (int mf=0; mf<2; ++mf){
    #pragma unroll
    for (int q=0; q<4; ++q){
      const int m = m_base + m0w + mf*16 + hi*4 + q;
      u16* xr = xpo + (size_t)m*4096 + hcol;
      xr[0]    = f2bf(acc[mf][0][q]);
      xr[1024] = f2bf(acc[mf][1][q]);
      xr[2048] = f2bf(acc[mf][2][q]);
      xr[3072] = f2bf(acc[mf][3][q]);
    }
  }
}

// ---- merged dispatch: blocks [0,384) = diag (L0@d, L1@d-5, L2@d-10);
// blocks [384,896) = xp window-4 (d%4==0: xp1 w=(d-4)/4; d%4==1: xp2 w=(d-9)/4).
__global__ __launch_bounds__(256)
void k_diag(int d, const int* __restrict__ x, u16* hist0, u16* hist1, u16* outsbF,
            float* __restrict__ cst, const u16* __restrict__ WpkH,
            const u16* __restrict__ WpkI,
            const float* __restrict__ bias0, const float* __restrict__ bcat,
            const u16* __restrict__ gxe, const u16* __restrict__ gxp,
            u16* __restrict__ xpb1, u16* __restrict__ xpb2)
{
  extern __shared__ u16 lds[];
  const int id = blockIdx.x;
  if (id < 384){
    const int mt = id / 192;
    const int slot = id - mt*192;
    const int layer = slot >> 6;
    const int jt = slot & 63;
    const int t = d - 5*layer;
    if (t < 0 || t > 98) return;
    if (layer == 0){
      diagh_tile<0>(mt, jt, t, x, hist0 + (size_t)((t+7)&7)*BH, hist0 + (size_t)(t&7)*BH,
                    cst, WpkH + (size_t)jt*65536, bias0, gxe, gxp, nullptr, lds);
    } else if (layer == 1){
      const u16* xpt = xpb1 + (size_t)((((t>>2)&1)<<2) + (t&3))*1048576;
      diagh_tile<1>(mt, jt, t, x, hist1 + (size_t)((t+7)&7)*BH, hist1 + (size_t)(t&7)*BH,
                    cst + BH, WpkH + (size_t)4194304 + (size_t)jt*65536, bcat,
                    nullptr, nullptr, xpt, lds);
    } else {
      const u16* xpt = xpb2 + (size_t)((((t>>2)&1)<<2) + (t&3))*1048576;
      diagh_tile<2>(mt, jt, t, x, outsbF + (size_t)t*BH, outsbF + (size_t)(t+1)*BH,
                    cst + 2*BH, WpkH + (size_t)8388608 + (size_t)jt*65536, bcat + 4096,
                    nullptr, nullptr, xpt, lds);
    }
  } else {
    const int idx = id - 384;                 // 512 blocks: tsub(4) x mt(2) x jt(64)
    const int jt = idx & 63;
    const int mtx = (idx >> 6) & 1;
    const int tsub = idx >> 7;
    const int m_base = mtx*128;
    int w; const u16* hist; const u16* Wblk; u16* xpo;
    if ((d & 3) == 0){ w = (d-4)>>2; hist = hist0; Wblk = WpkI;                   xpo = xpb1; }
    else             { w = (d-9)>>2; hist = hist1; Wblk = WpkI + (size_t)4194304; xpo = xpb2; }
    const int t = 4*w + tsub;
    if (t > 98) return;
    xp_tile(m_base, jt, hist + (size_t)(t&7)*BH, Wblk + (size_t)jt*65536,
            xpo + (size_t)(((w&1)<<2) + tsub)*1048576, lds);
  }
}

// ---- decoder: logits[b,t,v] = outs[t,b,:] . Wdec[v,:] + b_dec[v]
__global__ __launch_bounds__(256)
void k_decode(const u16* __restrict__ outs, const u16* __restrict__ Wdec,
              const float* __restrict__ bdec, float* __restrict__ logits){
  const int lane = threadIdx.x & 63, w = threadIdx.x >> 6;
  const int cl = lane & 15, ko = (lane >> 4)*8;
  const size_t m0 = ((size_t)blockIdx.x*4 + w)*16;
  const u16* ap = outs + (m0+cl)*1024 + ko;
  f32x4 acc[3];
  #pragma unroll
  for (int nt=0; nt<3; ++nt) acc[nt] = (f32x4){0.f,0.f,0.f,0.f};
  const u16* bp = Wdec + (size_t)cl*1024 + ko;
  for (int k0=0; k0<1024; k0+=32){
    bf16x8 a = *(const bf16x8*)(ap + k0);
    #pragma unroll
    for (int nt=0; nt<3; ++nt){
      bf16x8 b = *(const bf16x8*)(bp + (size_t)nt*16*1024 + k0);
      acc[nt] = MFMA16(a, b, acc[nt]);
    }
  }
  const int rbase = (lane >> 4)*4;
  #pragma unroll
  for (int nt=0; nt<3; ++nt){
    #pragma unroll
    for (int q=0; q<4; ++q){
      int v = nt*16 + cl;
      if (v < 47){
        size_t row = m0 + rbase + q;   // row = t*256 + b
        int tt = (int)(row >> 8);
        int b  = (int)(row & 255);
        logits[((size_t)b*99 + tt)*47 + v] = acc[nt][q] + bdec[v];
      }
    }
  }
}

// ---- final hT / cT copy-out (t=98: hist slots 98&7=2, outsbF slot 99)
__global__ void k_final(const u16* __restrict__ h0s, const u16* __restrict__ h1s,
                        const u16* __restrict__ h2s, const float* __restrict__ cst,
                        float* __restrict__ out){
  long i = (long)blockIdx.x*256 + threadIdx.x;
  if (i < (long)3*BH){
    int l = (int)(i >> 18); long r = i & (BH-1);
    const u16* src = (l==0) ? h0s : (l==1) ? h1s : h2s;
    out[1191168 + i] = bf2f(src[r]);
    out[1191168 + 786432 + i] = cst[i];
  }
}

extern "C" void kernel_launch(void* const* d_in, const int* in_sizes, int n_in,
                              void* d_out, int out_size, void* d_ws, size_t ws_size,
                              hipStream_t stream) {
  (void)in_sizes; (void)n_in; (void)out_size; (void)ws_size;
  const int*   x      = (const int*)  d_in[0];
  const float* props  = (const float*)d_in[1];
  const float* h0     = (const float*)d_in[2];
  const float* c0     = (const float*)d_in[3];
  const float* E      = (const float*)d_in[4];
  const float* W_ih0  = (const float*)d_in[5];
  const float* W_hh0  = (const float*)d_in[6];
  const float* b_ih0  = (const float*)d_in[7];
  const float* b_hh0  = (const float*)d_in[8];
  const float* W_ih_r = (const float*)d_in[9];
  const float* W_hh_r = (const float*)d_in[10];
  const float* b_ih_r = (const float*)d_in[11];
  const float* b_hh_r = (const float*)d_in[12];
  const float* W_dec  = (const float*)d_in[13];
  const float* b_dec  = (const float*)d_in[14];
  float* out = (float*)d_out;

  // workspace layout (~142 MB)
  u16* WpkH   = (u16*)d_ws;                 // 3 x 4,194,304 (W_hh stream blocks)
  u16* WpkI   = WpkH  + (size_t)12582912;   // 2 x 4,194,304 (W_ih_r stream blocks)
  u16* Wdec   = WpkI  + (size_t)8388608;    // 48*1024 (row 47 = 0)
  u16* Ebf    = Wdec  + (size_t)49152;      // 48*1024 (row 47 = 0)
  u16* hist0  = Ebf   + (size_t)49152;      // 8 x BH  (h0 ring; slot 7 = init)
  u16* hist1  = hist0 + (size_t)8*BH;       // 8 x BH
  u16* outsbF = hist1 + (size_t)8*BH;       // 100 x BH (slot 0 = h2 init; t -> t+1)
  u16* xpb1   = outsbF + (size_t)100*BH;    // [2 win-parity][4 tsub][256][4096] bf16
  u16* xpb2   = xpb1  + (size_t)8388608;    // same
  u16* Wih0b  = xpb1;                       // ALIAS: prep-only, dead before xp writes
  u16* gxe    = xpb2  + (size_t)8388608;    // 48*4096 bf16
  u16* gxp    = gxe   + (size_t)196608;     // 256*4096 bf16
  float* bias0 = (float*)(gxp + (size_t)1048576);  // 4096
  float* bcat  = bias0 + 4096;                     // 2*4096
  float* cst   = bcat  + 8192;                     // 3 x BH f32

  // ---- prep
  k_repackB<<<2048, 256, 0, stream>>>(W_hh0, W_hh0, WpkH, 16);
  k_repackB<<<2048, 256, 0, stream>>>(W_hh_r, W_hh_r, WpkH + (size_t)4194304, 16);
  k_repackB<<<2048, 256, 0, stream>>>(W_hh_r + (size_t)4194304, W_hh_r + (size_t)4194304,
                                      WpkH + (size_t)8388608, 16);
  k_repackB<<<2048, 256, 0, stream>>>(W_ih_r, W_ih_r, WpkI, 16);
  k_repackB<<<2048, 256, 0, stream>>>(W_ih_r + (size_t)4194304, W_ih_r + (size_t)4194304,
                                      WpkI + (size_t)4194304, 16);
  k_conv<<<2048, 256, 0, stream>>>(W_ih0, Wih0b, (long)4096*1024, 1024, 1027, 1024, 0);
  k_conv<<<24,   256, 0, stream>>>(E,     Ebf,   (long)47*1024,   1024, 1024, 1024, 0);
  k_conv<<<24,   256, 0, stream>>>(W_dec, Wdec,  (long)47*1024,   1024, 1024, 1024, 0);
  k_misc<<<7221, 256, 0, stream>>>(b_ih0, b_hh0, b_ih_r, b_hh_r, h0, c0, props, W_ih0,
                                   Ebf, Wdec, bias0, bcat, hist0, hist1, outsbF, cst, gxp);
  k_gxemb<<<dim3(3,256), 64, 0, stream>>>(Ebf, Wih0b, gxe);

  // ---- merged recurrence: d runs (L0@d, L1@d-5, L2@d-10) + one xp window-4
  (void)hipFuncSetAttribute(reinterpret_cast<const void*>(k_diag),
                            hipFuncAttributeMaxDynamicSharedMemorySize, 75776);
  for (int d = 0; d <= 108; ++d){
    bool hx = ((d & 3) == 0) ? (d >= 4 && d <= 100)
            : ((d & 3) == 1) ? (d >= 9 && d <= 105) : false;
    k_diag<<<384 + (hx ? 512 : 0), 256, 75776, stream>>>(
        d, x, hist0, hist1, outsbF, cst, WpkH, WpkI,
        bias0, bcat, gxe, gxp, xpb1, xpb2);
  }

  // ---- decode + final states
  k_decode<<<396, 256, 0, stream>>>(outsbF + (size_t)BH, Wdec, b_dec, out);
  k_final<<<3072, 256, 0, stream>>>(hist0 + (size_t)2*BH, hist1 + (size_t)2*BH,
                                    outsbF + (size_t)99*BH, cst, out);
}

// Round 15
// 2591.797 us; speedup vs baseline: 1.9602x; 1.0599x over previous
//
#include <hip/hip_runtime.h>

// ConditionalSmilesRnn: 3-layer LSTM, B=256, H=1024, steps=99, V=47, P=3.
// R15 = R9 (best, 2474us) + two isolated byte-reduction wins from R14,
// WITHOUT the pretouch (same-address trash-LDS writes serialized the LDS
// write port -- the R14 regression). Changes vs R9: (1) window-4 xp batches
// (skews {0,5,10}; xp1 at d%4==0, xp2 at d%4==1; halves W_ih refetch),
// (2) gxe/gxp stored bf16 (-2.4MB per L0 read).

typedef unsigned short u16;
typedef __bf16 bf16x8 __attribute__((ext_vector_type(8)));
typedef float f32x4 __attribute__((ext_vector_type(4)));
typedef u16 u16x8 __attribute__((ext_vector_type(8)));

#define MFMA16(a,b,c) __builtin_amdgcn_mfma_f32_16x16x32_bf16((a),(b),(c),0,0,0)
#define BH 262144

__device__ __forceinline__ u16 f2bf(float f){
  unsigned u = __builtin_bit_cast(unsigned, f);
  u += 0x7fffu + ((u >> 16) & 1u);          // RN-even
  return (u16)(u >> 16);
}
__device__ __forceinline__ float bf2f(u16 s){
  unsigned u = ((unsigned)s) << 16;
  return __builtin_bit_cast(float, u);
}
__device__ __forceinline__ float sigm(float x){ return 1.f/(1.f+__expf(-x)); }
__device__ __forceinline__ float tanhfast(float x){ return 1.f - 2.f/(__expf(2.f*x)+1.f); }

__device__ __forceinline__ void ld_lds16(const u16* g, u16* l){
  __builtin_amdgcn_global_load_lds((const __attribute__((address_space(1))) void*)g,
                                   (__attribute__((address_space(3))) void*)l, 16, 0, 0);
}

// ---- f32 -> bf16 strided converter
__global__ void k_conv(const float* __restrict__ src, u16* __restrict__ dst,
                       long total, int srow, int sstride, int dstride, int doff){
  long i = ((long)blockIdx.x*blockDim.x + threadIdx.x)*8;
  if (i >= total) return;
  long r = i / srow;
  int  k = (int)(i - r*srow);
  const float* s = src + r*(long)sstride + k;
  u16x8 o;
  #pragma unroll
  for (int j=0;j<8;++j) o[j] = f2bf(s[j]);
  *(u16x8*)(dst + r*(long)dstride + doff + k) = o;
}

// ---- weight repack into per-(jt) contiguous stream blocks (K=1024, nkt=16).
__global__ void k_repackB(const float* __restrict__ Wih, const float* __restrict__ Whh,
                          u16* __restrict__ dst, int nkt){
  long p = (long)blockIdx.x*256 + threadIdx.x;
  int G = (int)(p & 511);
  long q = p >> 9;
  int kt = (int)(q % nkt);
  int jt = (int)(q / nkt);
  int r = G >> 3, s = G & 7;
  int kk = kt*64 + ((s ^ (r & 7)) << 3);
  int n = (r >> 4)*1024 + jt*16 + (r & 15);
  const float* src = (kk < 1024) ? Wih + (size_t)n*1024 + kk
                                 : Whh + (size_t)n*1024 + (kk - 1024);
  u16x8 o;
  #pragma unroll
  for (int j=0;j<8;++j) o[j] = f2bf(src[j]);
  *(u16x8*)(dst + p*8) = o;
}

// ---- misc prep: biases, pad-row zeroing, state init (hist rings), gx_prop(bf16)
__global__ void k_misc(const float* __restrict__ b_ih0, const float* __restrict__ b_hh0,
                       const float* __restrict__ b_ihr, const float* __restrict__ b_hhr,
                       const float* __restrict__ h0, const float* __restrict__ c0,
                       const float* __restrict__ props, const float* __restrict__ W_ih0,
                       u16* __restrict__ Ebf, u16* __restrict__ Wdec,
                       float* __restrict__ bias0, float* __restrict__ bcat,
                       u16* __restrict__ hist0, u16* __restrict__ hist1,
                       u16* __restrict__ outsbF,
                       float* __restrict__ cst, u16* __restrict__ gxp){
  long i = (long)blockIdx.x*256 + threadIdx.x;
  if (i < 4096){ bias0[i] = b_ih0[i] + b_hh0[i]; return; }
  i -= 4096;
  if (i < 2*4096){ bcat[i] = b_ihr[i] + b_hhr[i]; return; }
  i -= 2*4096;
  if (i < 1024){ Ebf[47*1024 + i] = 0; Wdec[47*1024 + i] = 0; return; }
  i -= 1024;
  if (i < (long)3*BH){
    int l = (int)(i >> 18); long r = i & (BH-1);
    u16 v = f2bf(h0[i]);
    if (l==0)      hist0[(size_t)7*BH + r] = v;
    else if (l==1) hist1[(size_t)7*BH + r] = v;
    else           outsbF[r] = v;
    cst[i] = c0[i];
    return;
  }
  i -= (long)3*BH;
  if (i < (long)256*4096){
    int b = (int)(i >> 12), n = (int)(i & 4095);
    const float* wr = W_ih0 + (long)n*1027 + 1024;
    gxp[i] = f2bf(props[b*3+0]*wr[0] + props[b*3+1]*wr[1] + props[b*3+2]*wr[2]);
  }
}

// ---- gx_emb[v][n] = sum_k E[v][k] * W_ih0[n][k] -> bf16
__global__ __launch_bounds__(64)
void k_gxemb(const u16* __restrict__ Ebf, const u16* __restrict__ Wih0b, u16* __restrict__ gxe){
  const int lane = threadIdx.x;
  const int cl = lane & 15, ko = (lane >> 4)*8;
  const int m0 = blockIdx.x*16;
  const int n0 = blockIdx.y*16;
  f32x4 acc = {0.f,0.f,0.f,0.f};
  const u16* ap = Ebf   + (size_t)(m0+cl)*1024 + ko;
  const u16* bp = Wih0b + (size_t)(n0+cl)*1024 + ko;
  for (int k0=0; k0<1024; k0+=32){
    bf16x8 a = *(const bf16x8*)(ap + k0);
    bf16x8 b = *(const bf16x8*)(bp + k0);
    acc = MFMA16(a, b, acc);
  }
  const int rbase = (lane >> 4)*4;
  #pragma unroll
  for (int q=0;q<4;++q){
    int v = m0 + rbase + q;
    if (v < 47) gxe[(size_t)v*4096 + n0 + cl] = f2bf(acc[q]);
  }
}

// ================= shared K-loop (TM=128 x TN=64, K=1024, NT=16) =================
// R9's exact pipeline: 3 LDS slots x 24KB, 2-deep prefetch, one barrier per
// chunk, counted vmcnt(6), setprio around the MFMA cluster.
#define KLOOP_BODY(APTR_EXPR)                                                   \
  auto stage = [&](int s, int kt){                                              \
    const int kbase = kt*64;                                                    \
    u16* sA = lds + (size_t)s*12288;                                            \
    u16* sB = sA + 8192;                                                        \
    _Pragma("unroll")                                                           \
    for (int j=0;j<4;++j){                                                      \
      int G = j*256 + tid; int r = G >> 3;                                      \
      int kk = kbase + (((G & 7) ^ (r & 7)) << 3);                              \
      ld_lds16(APTR_EXPR, sA + (size_t)G*8);                                    \
    }                                                                           \
    _Pragma("unroll")                                                           \
    for (int j=0;j<2;++j){                                                      \
      int G = j*256 + tid;                                                      \
      ld_lds16(Bblk + (size_t)kt*4096 + (size_t)G*8, sB + (size_t)G*8);         \
    }                                                                           \
  };                                                                            \
  f32x4 acc[2][4];                                                              \
  _Pragma("unroll")                                                             \
  for (int mf=0; mf<2; ++mf)                                                    \
    _Pragma("unroll")                                                           \
    for (int g=0; g<4; ++g) acc[mf][g] = (f32x4){0.f,0.f,0.f,0.f};              \
  stage(0,0); stage(1,1);                                                       \
  for (int kt=0; kt<16; ++kt){                                                  \
    if (kt == 15) asm volatile("s_waitcnt vmcnt(0)" ::: "memory");              \
    else          asm volatile("s_waitcnt vmcnt(6)" ::: "memory");              \
    __builtin_amdgcn_s_barrier();                                               \
    asm volatile("" ::: "memory");                                              \
    if (kt+2 < 16) stage((kt+2)%3, kt+2);                                       \
    const u16* A = lds + (size_t)(kt%3)*12288;                                  \
    const u16* B = A + 8192;                                                    \
    __builtin_amdgcn_s_setprio(1);                                              \
    _Pragma("unroll")                                                           \
    for (int half=0; half<2; ++half){                                           \
      const int kg = half*4 + hi;                                               \
      bf16x8 a0, a1, b[4];                                                      \
      { int r = m0w + cl;      a0 = *(const bf16x8*)(A + r*64 + ((kg ^ (r&7))<<3)); } \
      { int r = m0w + 16 + cl; a1 = *(const bf16x8*)(A + r*64 + ((kg ^ (r&7))<<3)); } \
      _Pragma("unroll")                                                         \
      for (int g=0; g<4; ++g){                                                  \
        int r = g*16 + cl;                                                      \
        b[g] = *(const bf16x8*)(B + r*64 + ((kg ^ (r&7))<<3));                  \
      }                                                                         \
      _Pragma("unroll")                                                         \
      for (int g=0; g<4; ++g){                                                  \
        acc[0][g] = MFMA16(a0, b[g], acc[0][g]);                                \
        acc[1][g] = MFMA16(a1, b[g], acc[1][g]);                                \
      }                                                                         \
    }                                                                           \
    __builtin_amdgcn_s_setprio(0);                                              \
    asm volatile("" ::: "memory");                                              \
  }

// ---- diag tile: gates = W_hh . h_prev (+ gxe/gxp or xpart) + bias; fused cell.
template<int LAYER>
__device__ __forceinline__ void diagh_tile(int mt, int jt, int t,
    const int* __restrict__ x, const u16* hp, u16* aux, float* cc,
    const u16* __restrict__ Bblk, const float* __restrict__ bias,
    const u16* __restrict__ gxe, const u16* __restrict__ gxp,
    const u16* xpt, u16* lds)
{
  const int tid = threadIdx.x;
  const int lane = tid & 63, w = tid >> 6;
  const int cl = lane & 15, hi = lane >> 4;
  const int m_base = mt*128, m0w = w*32;

  KLOOP_BODY(hp + (size_t)(m_base + r)*1024 + kk)

  // fused LSTM cell. C/D: col = cl (-> hcol), row = hi*4+q (-> batch)
  const int hcol = jt*16 + cl;
  const float bi_ = bias[hcol], bf_ = bias[1024+hcol],
              bg_ = bias[2048+hcol], bo_ = bias[3072+hcol];
  #pragma unroll
  for (int mf=0; mf<2; ++mf){
    #pragma unroll
    for (int q=0; q<4; ++q){
      const int row = m_base + m0w + mf*16 + hi*4 + q;
      float gi = acc[mf][0][q] + bi_;
      float gf = acc[mf][1][q] + bf_;
      float gg = acc[mf][2][q] + bg_;
      float go = acc[mf][3][q] + bo_;
      if (LAYER == 0){
        const int tok = (t==0) ? 1 : x[row*100 + t];
        const u16* ge = gxe + (size_t)tok*4096;
        const u16* gp = gxp + (size_t)row*4096;
        gi += bf2f(ge[hcol])        + bf2f(gp[hcol]);
        gf += bf2f(ge[1024 + hcol]) + bf2f(gp[1024 + hcol]);
        gg += bf2f(ge[2048 + hcol]) + bf2f(gp[2048 + hcol]);
        go += bf2f(ge[3072 + hcol]) + bf2f(gp[3072 + hcol]);
      } else {
        const u16* xr = xpt + (size_t)row*4096;
        gi += bf2f(xr[hcol]);
        gf += bf2f(xr[1024 + hcol]);
        gg += bf2f(xr[2048 + hcol]);
        go += bf2f(xr[3072 + hcol]);
      }
      const float i_ = sigm(gi), f_ = sigm(gf), o_ = sigm(go), g_ = tanhfast(gg);
      const size_t off = (size_t)row*1024 + hcol;
      const float cn = f_*cc[off] + i_*g_;
      cc[off] = cn;
      aux[off] = f2bf(o_*tanhfast(cn));
    }
  }
}

// ---- xp tile: xpart rows [m_base, m_base+128) of one step t -> bf16
__device__ __forceinline__ void xp_tile(int m_base, int jt,
    const u16* hp, const u16* __restrict__ Bblk, u16* xpo, u16* lds)
{
  const int tid = threadIdx.x;
  const int lane = tid & 63, w = tid >> 6;
  const int cl = lane & 15, hi = lane >> 4;
  const int m0w = w*32;

  KLOOP_BODY(hp + (size_t)(m_base + r)*1024 + kk)

  const int hcol = jt*16 + cl;
  #pragma unroll
  for (int mf=0; mf<2; ++mf){
    #pragma unroll
    for (int q=0; q<4; ++q){
      const int m = m_base + m0w + mf*16 + hi*4 + q;
      u16* xr = xpo + (size_t)m*4096 + hcol;
      xr[0]    = f2bf(acc[mf][0][q]);
      xr[1024] = f2bf(acc[mf][1][q]);
      xr[2048] = f2bf(acc[mf][2][q]);
      xr[3072] = f2bf(acc[mf][3][q]);
    }
  }
}

// ---- merged dispatch: blocks [0,384) = diag (L0@d, L1@d-5, L2@d-10);
// blocks [384,896) = xp window-4 (d%4==0: xp1 w=(d-4)/4; d%4==1: xp2 w=(d-9)/4).
__global__ __launch_bounds__(256)
void k_diag(int d, const int* __restrict__ x, u16* hist0, u16* hist1, u16* outsbF,
            float* __restrict__ cst, const u16* __restrict__ WpkH,
            const u16* __restrict__ WpkI,
            const float* __restrict__ bias0, const float* __restrict__ bcat,
            const u16* __restrict__ gxe, const u16* __restrict__ gxp,
            u16* __restrict__ xpb1, u16* __restrict__ xpb2)
{
  extern __shared__ u16 lds[];
  const int id = blockIdx.x;
  if (id < 384){
    const int mt = id / 192;
    const int slot = id - mt*192;
    const int layer = slot >> 6;
    const int jt = slot & 63;
    const int t = d - 5*layer;
    if (t < 0 || t > 98) return;
    if (layer == 0){
      diagh_tile<0>(mt, jt, t, x, hist0 + (size_t)((t+7)&7)*BH, hist0 + (size_t)(t&7)*BH,
                    cst, WpkH + (size_t)jt*65536, bias0, gxe, gxp, nullptr, lds);
    } else if (layer == 1){
      const u16* xpt = xpb1 + (size_t)((((t>>2)&1)<<2) + (t&3))*1048576;
      diagh_tile<1>(mt, jt, t, x, hist1 + (size_t)((t+7)&7)*BH, hist1 + (size_t)(t&7)*BH,
                    cst + BH, WpkH + (size_t)4194304 + (size_t)jt*65536, bcat,
                    nullptr, nullptr, xpt, lds);
    } else {
      const u16* xpt = xpb2 + (size_t)((((t>>2)&1)<<2) + (t&3))*1048576;
      diagh_tile<2>(mt, jt, t, x, outsbF + (size_t)t*BH, outsbF + (size_t)(t+1)*BH,
                    cst + 2*BH, WpkH + (size_t)8388608 + (size_t)jt*65536, bcat + 4096,
                    nullptr, nullptr, xpt, lds);
    }
  } else {
    const int idx = id - 384;                 // 512 blocks: tsub(4) x mt(2) x jt(64)
    const int jt = idx & 63;
    const int mtx = (idx >> 6) & 1;
    const int tsub = idx >> 7;
    const int m_base = mtx*128;
    int w; const u16* hist; const u16* Wblk; u16* xpo;
    if ((d & 3) == 0){ w = (d-4)>>2; hist = hist0; Wblk = WpkI;                   xpo = xpb1; }
    else             { w = (d-9)>>2; hist = hist1; Wblk = WpkI + (size_t)4194304; xpo = xpb2; }
    const int t = 4*w + tsub;
    if (t > 98) return;
    xp_tile(m_base, jt, hist + (size_t)(t&7)*BH, Wblk + (size_t)jt*65536,
            xpo + (size_t)(((w&1)<<2) + tsub)*1048576, lds);
  }
}

// ---- decoder: logits[b,t,v] = outs[t,b,:] . Wdec[v,:] + b_dec[v]
__global__ __launch_bounds__(256)
void k_decode(const u16* __restrict__ outs, const u16* __restrict__ Wdec,
              const float* __restrict__ bdec, float* __restrict__ logits){
  const int lane = threadIdx.x & 63, w = threadIdx.x >> 6;
  const int cl = lane & 15, ko = (lane >> 4)*8;
  const size_t m0 = ((size_t)blockIdx.x*4 + w)*16;
  const u16* ap = outs + (m0+cl)*1024 + ko;
  f32x4 acc[3];
  #pragma unroll
  for (int nt=0; nt<3; ++nt) acc[nt] = (f32x4){0.f,0.f,0.f,0.f};
  const u16* bp = Wdec + (size_t)cl*1024 + ko;
  for (int k0=0; k0<1024; k0+=32){
    bf16x8 a = *(const bf16x8*)(ap + k0);
    #pragma unroll
    for (int nt=0; nt<3; ++nt){
      bf16x8 b = *(const bf16x8*)(bp + (size_t)nt*16*1024 + k0);
      acc[nt] = MFMA16(a, b, acc[nt]);
    }
  }
  const int rbase = (lane >> 4)*4;
  #pragma unroll
  for (int nt=0; nt<3; ++nt){
    #pragma unroll
    for (int q=0; q<4; ++q){
      int v = nt*16 + cl;
      if (v < 47){
        size_t row = m0 + rbase + q;   // row = t*256 + b
        int tt = (int)(row >> 8);
        int b  = (int)(row & 255);
        logits[((size_t)b*99 + tt)*47 + v] = acc[nt][q] + bdec[v];
      }
    }
  }
}

// ---- final hT / cT copy-out (t=98: hist slots 98&7=2, outsbF slot 99)
__global__ void k_final(const u16* __restrict__ h0s, const u16* __restrict__ h1s,
                        const u16* __restrict__ h2s, const float* __restrict__ cst,
                        float* __restrict__ out){
  long i = (long)blockIdx.x*256 + threadIdx.x;
  if (i < (long)3*BH){
    int l = (int)(i >> 18); long r = i & (BH-1);
    const u16* src = (l==0) ? h0s : (l==1) ? h1s : h2s;
    out[1191168 + i] = bf2f(src[r]);
    out[1191168 + 786432 + i] = cst[i];
  }
}

extern "C" void kernel_launch(void* const* d_in, const int* in_sizes, int n_in,
                              void* d_out, int out_size, void* d_ws, size_t ws_size,
                              hipStream_t stream) {
  (void)in_sizes; (void)n_in; (void)out_size; (void)ws_size;
  const int*   x      = (const int*)  d_in[0];
  const float* props  = (const float*)d_in[1];
  const float* h0     = (const float*)d_in[2];
  const float* c0     = (const float*)d_in[3];
  const float* E      = (const float*)d_in[4];
  const float* W_ih0  = (const float*)d_in[5];
  const float* W_hh0  = (const float*)d_in[6];
  const float* b_ih0  = (const float*)d_in[7];
  const float* b_hh0  = (const float*)d_in[8];
  const float* W_ih_r = (const float*)d_in[9];
  const float* W_hh_r = (const float*)d_in[10];
  const float* b_ih_r = (const float*)d_in[11];
  const float* b_hh_r = (const float*)d_in[12];
  const float* W_dec  = (const float*)d_in[13];
  const float* b_dec  = (const float*)d_in[14];
  float* out = (float*)d_out;

  // workspace layout (~142 MB)
  u16* WpkH   = (u16*)d_ws;                 // 3 x 4,194,304 (W_hh stream blocks)
  u16* WpkI   = WpkH  + (size_t)12582912;   // 2 x 4,194,304 (W_ih_r stream blocks)
  u16* Wdec   = WpkI  + (size_t)8388608;    // 48*1024 (row 47 = 0)
  u16* Ebf    = Wdec  + (size_t)49152;      // 48*1024 (row 47 = 0)
  u16* hist0  = Ebf   + (size_t)49152;      // 8 x BH  (h0 ring; slot 7 = init)
  u16* hist1  = hist0 + (size_t)8*BH;       // 8 x BH
  u16* outsbF = hist1 + (size_t)8*BH;       // 100 x BH (slot 0 = h2 init; t -> t+1)
  u16* xpb1   = outsbF + (size_t)100*BH;    // [2 win-parity][4 tsub][256][4096] bf16
  u16* xpb2   = xpb1  + (size_t)8388608;    // same
  u16* Wih0b  = xpb1;                       // ALIAS: prep-only, dead before xp writes
  u16* gxe    = xpb2  + (size_t)8388608;    // 48*4096 bf16
  u16* gxp    = gxe   + (size_t)196608;     // 256*4096 bf16
  float* bias0 = (float*)(gxp + (size_t)1048576);  // 4096
  float* bcat  = bias0 + 4096;                     // 2*4096
  float* cst   = bcat  + 8192;                     // 3 x BH f32

  // ---- prep
  k_repackB<<<2048, 256, 0, stream>>>(W_hh0, W_hh0, WpkH, 16);
  k_repackB<<<2048, 256, 0, stream>>>(W_hh_r, W_hh_r, WpkH + (size_t)4194304, 16);
  k_repackB<<<2048, 256, 0, stream>>>(W_hh_r + (size_t)4194304, W_hh_r + (size_t)4194304,
                                      WpkH + (size_t)8388608, 16);
  k_repackB<<<2048, 256, 0, stream>>>(W_ih_r, W_ih_r, WpkI, 16);
  k_repackB<<<2048, 256, 0, stream>>>(W_ih_r + (size_t)4194304, W_ih_r + (size_t)4194304,
                                      WpkI + (size_t)4194304, 16);
  k_conv<<<2048, 256, 0, stream>>>(W_ih0, Wih0b, (long)4096*1024, 1024, 1027, 1024, 0);
  k_conv<<<24,   256, 0, stream>>>(E,     Ebf,   (long)47*1024,   1024, 1024, 1024, 0);
  k_conv<<<24,   256, 0, stream>>>(W_dec, Wdec,  (long)47*1024,   1024, 1024, 1024, 0);
  k_misc<<<7221, 256, 0, stream>>>(b_ih0, b_hh0, b_ih_r, b_hh_r, h0, c0, props, W_ih0,
                                   Ebf, Wdec, bias0, bcat, hist0, hist1, outsbF, cst, gxp);
  k_gxemb<<<dim3(3,256), 64, 0, stream>>>(Ebf, Wih0b, gxe);

  // ---- merged recurrence: d runs (L0@d, L1@d-5, L2@d-10) + one xp window-4
  (void)hipFuncSetAttribute(reinterpret_cast<const void*>(k_diag),
                            hipFuncAttributeMaxDynamicSharedMemorySize, 73728);
  for (int d = 0; d <= 108; ++d){
    bool hx = ((d & 3) == 0) ? (d >= 4 && d <= 100)
            : ((d & 3) == 1) ? (d >= 9 && d <= 105) : false;
    k_diag<<<384 + (hx ? 512 : 0), 256, 73728, stream>>>(
        d, x, hist0, hist1, outsbF, cst, WpkH, WpkI,
        bias0, bcat, gxe, gxp, xpb1, xpb2);
  }

  // ---- decode + final states
  k_decode<<<396, 256, 0, stream>>>(outsbF + (size_t)BH, Wdec, b_dec, out);
  k_final<<<3072, 256, 0, stream>>>(hist0 + (size_t)2*BH, hist1 + (size_t)2*BH,
                                    outsbF + (size_t)99*BH, cst, out);
}

// Round 16
// 2475.297 us; speedup vs baseline: 2.0524x; 1.0471x over previous
//
#include <hip/hip_runtime.h>

// ConditionalSmilesRnn: 3-layer LSTM, B=256, H=1024, steps=99, V=47, P=3.
// FINAL = R9 (best measured: 2474us). Single merged dispatch stream. Diag
// blocks (384) run the W_hh h-GEMMs (skew {0,3,6}) + fused cells; 256 extra
// blocks per dispatch run the W_ih x-GEMMs for a 2-step window (xp1 on even d,
// xp2 on odd d), fully overlapped. 105 dispatches total.
// (R10-R15 perturbations -- mega-dispatch, B-in-VGPR, 128x128 tiles,
// pretouch, window-4 xp, bf16 gx -- all regressed; see session journal.)

typedef unsigned short u16;
typedef __bf16 bf16x8 __attribute__((ext_vector_type(8)));
typedef float f32x4 __attribute__((ext_vector_type(4)));
typedef u16 u16x8 __attribute__((ext_vector_type(8)));

#define MFMA16(a,b,c) __builtin_amdgcn_mfma_f32_16x16x32_bf16((a),(b),(c),0,0,0)
#define BH 262144

__device__ __forceinline__ u16 f2bf(float f){
  unsigned u = __builtin_bit_cast(unsigned, f);
  u += 0x7fffu + ((u >> 16) & 1u);          // RN-even
  return (u16)(u >> 16);
}
__device__ __forceinline__ float bf2f(u16 s){
  unsigned u = ((unsigned)s) << 16;
  return __builtin_bit_cast(float, u);
}
__device__ __forceinline__ float sigm(float x){ return 1.f/(1.f+__expf(-x)); }
__device__ __forceinline__ float tanhfast(float x){ return 1.f - 2.f/(__expf(2.f*x)+1.f); }

__device__ __forceinline__ void ld_lds16(const u16* g, u16* l){
  __builtin_amdgcn_global_load_lds((const __attribute__((address_space(1))) void*)g,
                                   (__attribute__((address_space(3))) void*)l, 16, 0, 0);
}

// ---- f32 -> bf16 strided converter
__global__ void k_conv(const float* __restrict__ src, u16* __restrict__ dst,
                       long total, int srow, int sstride, int dstride, int doff){
  long i = ((long)blockIdx.x*blockDim.x + threadIdx.x)*8;
  if (i >= total) return;
  long r = i / srow;
  int  k = (int)(i - r*srow);
  const float* s = src + r*(long)sstride + k;
  u16x8 o;
  #pragma unroll
  for (int j=0;j<8;++j) o[j] = f2bf(s[j]);
  *(u16x8*)(dst + r*(long)dstride + doff + k) = o;
}

// ---- weight repack into per-(jt) contiguous stream blocks (K=1024, nkt=16).
// granule p = (jt*nkt + kt)*512 + r*8 + s; src row n = (r>>4)*1024 + jt*16 + (r&15);
// cols kk = kt*64 + ((s ^ (r&7))<<3)  (LDS swizzle baked in).
__global__ void k_repackB(const float* __restrict__ Wih, const float* __restrict__ Whh,
                          u16* __restrict__ dst, int nkt){
  long p = (long)blockIdx.x*256 + threadIdx.x;
  int G = (int)(p & 511);
  long q = p >> 9;
  int kt = (int)(q % nkt);
  int jt = (int)(q / nkt);
  int r = G >> 3, s = G & 7;
  int kk = kt*64 + ((s ^ (r & 7)) << 3);
  int n = (r >> 4)*1024 + jt*16 + (r & 15);
  const float* src = (kk < 1024) ? Wih + (size_t)n*1024 + kk
                                 : Whh + (size_t)n*1024 + (kk - 1024);
  u16x8 o;
  #pragma unroll
  for (int j=0;j<8;++j) o[j] = f2bf(src[j]);
  *(u16x8*)(dst + p*8) = o;
}

// ---- misc prep: biases, pad-row zeroing, state init (hist rings), gx_prop
__global__ void k_misc(const float* __restrict__ b_ih0, const float* __restrict__ b_hh0,
                       const float* __restrict__ b_ihr, const float* __restrict__ b_hhr,
                       const float* __restrict__ h0, const float* __restrict__ c0,
                       const float* __restrict__ props, const float* __restrict__ W_ih0,
                       u16* __restrict__ Ebf, u16* __restrict__ Wdec,
                       float* __restrict__ bias0, float* __restrict__ bcat,
                       u16* __restrict__ hist0, u16* __restrict__ hist1,
                       u16* __restrict__ outsbF,
                       float* __restrict__ cst, float* __restrict__ gxp){
  long i = (long)blockIdx.x*256 + threadIdx.x;
  if (i < 4096){ bias0[i] = b_ih0[i] + b_hh0[i]; return; }
  i -= 4096;
  if (i < 2*4096){ bcat[i] = b_ihr[i] + b_hhr[i]; return; }
  i -= 2*4096;
  if (i < 1024){ Ebf[47*1024 + i] = 0; Wdec[47*1024 + i] = 0; return; }
  i -= 1024;
  if (i < (long)3*BH){
    int l = (int)(i >> 18); long r = i & (BH-1);
    u16 v = f2bf(h0[i]);
    if (l==0)      hist0[(size_t)7*BH + r] = v;
    else if (l==1) hist1[(size_t)7*BH + r] = v;
    else           outsbF[r] = v;
    cst[i] = c0[i];
    return;
  }
  i -= (long)3*BH;
  if (i < (long)256*4096){
    int b = (int)(i >> 12), n = (int)(i & 4095);
    const float* wr = W_ih0 + (long)n*1027 + 1024;
    gxp[i] = props[b*3+0]*wr[0] + props[b*3+1]*wr[1] + props[b*3+2]*wr[2];
  }
}

// ---- gx_emb[v][n] = sum_k E[v][k] * W_ih0[n][k]  (M=48 padded, N=4096, K=1024)
__global__ __launch_bounds__(64)
void k_gxemb(const u16* __restrict__ Ebf, const u16* __restrict__ Wih0b, float* __restrict__ gxe){
  const int lane = threadIdx.x;
  const int cl = lane & 15, ko = (lane >> 4)*8;
  const int m0 = blockIdx.x*16;
  const int n0 = blockIdx.y*16;
  f32x4 acc = {0.f,0.f,0.f,0.f};
  const u16* ap = Ebf   + (size_t)(m0+cl)*1024 + ko;
  const u16* bp = Wih0b + (size_t)(n0+cl)*1024 + ko;
  for (int k0=0; k0<1024; k0+=32){
    bf16x8 a = *(const bf16x8*)(ap + k0);
    bf16x8 b = *(const bf16x8*)(bp + k0);
    acc = MFMA16(a, b, acc);
  }
  const int rbase = (lane >> 4)*4;
  #pragma unroll
  for (int q=0;q<4;++q){
    int v = m0 + rbase + q;
    if (v < 47) gxe[(size_t)v*4096 + n0 + cl] = acc[q];
  }
}

// ================= shared K-loop (TM=128 x TN=64, K=1024, NT=16) =================
// 3 LDS slots x 24KB (pointer arithmetic only), 2-deep prefetch, one barrier
// per chunk, counted vmcnt, setprio around compute.
#define KLOOP_BODY(APTR_EXPR)                                                   \
  auto stage = [&](int s, int kt){                                              \
    const int kbase = kt*64;                                                    \
    u16* sA = lds + (size_t)s*12288;                                            \
    u16* sB = sA + 8192;                                                        \
    _Pragma("unroll")                                                           \
    for (int j=0;j<4;++j){                                                      \
      int G = j*256 + tid; int r = G >> 3;                                      \
      int kk = kbase + (((G & 7) ^ (r & 7)) << 3);                              \
      ld_lds16(APTR_EXPR, sA + (size_t)G*8);                                    \
    }                                                                           \
    _Pragma("unroll")                                                           \
    for (int j=0;j<2;++j){                                                      \
      int G = j*256 + tid;                                                      \
      ld_lds16(Bblk + (size_t)kt*4096 + (size_t)G*8, sB + (size_t)G*8);         \
    }                                                                           \
  };                                                                            \
  f32x4 acc[2][4];                                                              \
  _Pragma("unroll")                                                             \
  for (int mf=0; mf<2; ++mf)                                                    \
    _Pragma("unroll")                                                           \
    for (int g=0; g<4; ++g) acc[mf][g] = (f32x4){0.f,0.f,0.f,0.f};              \
  stage(0,0); stage(1,1);                                                       \
  for (int kt=0; kt<16; ++kt){                                                  \
    if (kt == 15) asm volatile("s_waitcnt vmcnt(0)" ::: "memory");              \
    else          asm volatile("s_waitcnt vmcnt(6)" ::: "memory");              \
    __builtin_amdgcn_s_barrier();                                               \
    asm volatile("" ::: "memory");                                              \
    if (kt+2 < 16) stage((kt+2)%3, kt+2);                                       \
    const u16* A = lds + (size_t)(kt%3)*12288;                                  \
    const u16* B = A + 8192;                                                    \
    __builtin_amdgcn_s_setprio(1);                                              \
    _Pragma("unroll")                                                           \
    for (int half=0; half<2; ++half){                                           \
      const int kg = half*4 + hi;                                               \
      bf16x8 a0, a1, b[4];                                                      \
      { int r = m0w + cl;      a0 = *(const bf16x8*)(A + r*64 + ((kg ^ (r&7))<<3)); } \
      { int r = m0w + 16 + cl; a1 = *(const bf16x8*)(A + r*64 + ((kg ^ (r&7))<<3)); } \
      _Pragma("unroll")                                                         \
      for (int g=0; g<4; ++g){                                                  \
        int r = g*16 + cl;                                                      \
        b[g] = *(const bf16x8*)(B + r*64 + ((kg ^ (r&7))<<3));                  \
      }                                                                         \
      _Pragma("unroll")                                                         \
      for (int g=0; g<4; ++g){                                                  \
        acc[0][g] = MFMA16(a0, b[g], acc[0][g]);                                \
        acc[1][g] = MFMA16(a1, b[g], acc[1][g]);                                \
      }                                                                         \
    }                                                                           \
    __builtin_amdgcn_s_setprio(0);                                              \
    asm volatile("" ::: "memory");                                              \
  }

// ---- diag tile: gates = W_hh . h_prev (+ gxe/gxp or xpart) + bias; fused cell.
template<int LAYER>
__device__ __forceinline__ void diagh_tile(int mt, int jt, int t,
    const int* __restrict__ x, const u16* hp, u16* aux, float* cc,
    const u16* __restrict__ Bblk, const float* __restrict__ bias,
    const float* __restrict__ gxe, const float* __restrict__ gxp,
    const u16* xpt, u16* lds)
{
  const int tid = threadIdx.x;
  const int lane = tid & 63, w = tid >> 6;
  const int cl = lane & 15, hi = lane >> 4;
  const int m_base = mt*128, m0w = w*32;

  KLOOP_BODY(hp + (size_t)(m_base + r)*1024 + kk)

  // fused LSTM cell. C/D: col = cl (-> hcol), row = hi*4+q (-> batch)
  const int hcol = jt*16 + cl;
  const float bi_ = bias[hcol], bf_ = bias[1024+hcol],
              bg_ = bias[2048+hcol], bo_ = bias[3072+hcol];
  #pragma unroll
  for (int mf=0; mf<2; ++mf){
    #pragma unroll
    for (int q=0; q<4; ++q){
      const int row = m_base + m0w + mf*16 + hi*4 + q;
      float gi = acc[mf][0][q] + bi_;
      float gf = acc[mf][1][q] + bf_;
      float gg = acc[mf][2][q] + bg_;
      float go = acc[mf][3][q] + bo_;
      if (LAYER == 0){
        const int tok = (t==0) ? 1 : x[row*100 + t];
        const float* ge = gxe + (size_t)tok*4096;
        const float* gp = gxp + (size_t)row*4096;
        gi += ge[hcol]        + gp[hcol];
        gf += ge[1024 + hcol] + gp[1024 + hcol];
        gg += ge[2048 + hcol] + gp[2048 + hcol];
        go += ge[3072 + hcol] + gp[3072 + hcol];
      } else {
        const u16* xr = xpt + (size_t)row*4096;
        gi += bf2f(xr[hcol]);
        gf += bf2f(xr[1024 + hcol]);
        gg += bf2f(xr[2048 + hcol]);
        go += bf2f(xr[3072 + hcol]);
      }
      const float i_ = sigm(gi), f_ = sigm(gf), o_ = sigm(go), g_ = tanhfast(gg);
      const size_t off = (size_t)row*1024 + hcol;
      const float cn = f_*cc[off] + i_*g_;
      cc[off] = cn;
      aux[off] = f2bf(o_*tanhfast(cn));
    }
  }
}

// ---- xp tile: xpart rows [m_base, m_base+128) of one step t -> bf16
__device__ __forceinline__ void xp_tile(int m_base, int jt,
    const u16* hp, const u16* __restrict__ Bblk, u16* xpo, u16* lds)
{
  const int tid = threadIdx.x;
  const int lane = tid & 63, w = tid >> 6;
  const int cl = lane & 15, hi = lane >> 4;
  const int m0w = w*32;

  KLOOP_BODY(hp + (size_t)(m_base + r)*1024 + kk)

  const int hcol = jt*16 + cl;
  #pragma unroll
  for (int mf=0; mf<2; ++mf){
    #pragma unroll
    for (int q=0; q<4; ++q){
      const int m = m_base + m0w + mf*16 + hi*4 + q;
      u16* xr = xpo + (size_t)m*4096 + hcol;
      xr[0]    = f2bf(acc[mf][0][q]);
      xr[1024] = f2bf(acc[mf][1][q]);
      xr[2048] = f2bf(acc[mf][2][q]);
      xr[3072] = f2bf(acc[mf][3][q]);
    }
  }
}

// ---- merged dispatch: blocks [0,384) = diag (L0@d, L1@d-3, L2@d-6);
// blocks [384,640) = xp window (even d: xp1 w=(d-2)/2; odd d: xp2 w=(d-5)/2).
__global__ __launch_bounds__(256)
void k_diag(int d, const int* __restrict__ x, u16* hist0, u16* hist1, u16* outsbF,
            float* __restrict__ cst, const u16* __restrict__ WpkH,
            const u16* __restrict__ WpkI,
            const float* __restrict__ bias0, const float* __restrict__ bcat,
            const float* __restrict__ gxe, const float* __restrict__ gxp,
            u16* __restrict__ xpb1, u16* __restrict__ xpb2)
{
  extern __shared__ u16 lds[];
  const int id = blockIdx.x;
  if (id < 384){
    const int mt = id / 192;
    const int slot = id - mt*192;
    const int layer = slot >> 6;
    const int jt = slot & 63;
    const int t = d - 3*layer;
    if (t < 0 || t > 98) return;
    if (layer == 0){
      diagh_tile<0>(mt, jt, t, x, hist0 + (size_t)((t+7)&7)*BH, hist0 + (size_t)(t&7)*BH,
                    cst, WpkH + (size_t)jt*65536, bias0, gxe, gxp, nullptr, lds);
    } else if (layer == 1){
      const u16* xpt = xpb1 + (size_t)((((t>>1)&1)<<1) + (t&1))*1048576;
      diagh_tile<1>(mt, jt, t, x, hist1 + (size_t)((t+7)&7)*BH, hist1 + (size_t)(t&7)*BH,
                    cst + BH, WpkH + (size_t)4194304 + (size_t)jt*65536, bcat,
                    nullptr, nullptr, xpt, lds);
    } else {
      const u16* xpt = xpb2 + (size_t)((((t>>1)&1)<<1) + (t&1))*1048576;
      diagh_tile<2>(mt, jt, t, x, outsbF + (size_t)t*BH, outsbF + (size_t)(t+1)*BH,
                    cst + 2*BH, WpkH + (size_t)8388608 + (size_t)jt*65536, bcat + 4096,
                    nullptr, nullptr, xpt, lds);
    }
  } else {
    const int idx = id - 384;
    const int mtx = idx >> 6, jt = idx & 63;
    const int tsub = mtx >> 1, m_base = (mtx & 1)*128;
    int w; const u16* hist; const u16* Wblk; u16* xpo;
    if ((d & 1) == 0){ w = (d-2)>>1; hist = hist0; Wblk = WpkI;                     xpo = xpb1; }
    else             { w = (d-5)>>1; hist = hist1; Wblk = WpkI + (size_t)4194304;   xpo = xpb2; }
    const int t = 2*w + tsub;
    if (t > 98) return;
    xp_tile(m_base, jt, hist + (size_t)(t&7)*BH, Wblk + (size_t)jt*65536,
            xpo + (size_t)(((w&1)<<1) + tsub)*1048576, lds);
  }
}

// ---- decoder: logits[b,t,v] = outs[t,b,:] . Wdec[v,:] + b_dec[v]
__global__ __launch_bounds__(256)
void k_decode(const u16* __restrict__ outs, const u16* __restrict__ Wdec,
              const float* __restrict__ bdec, float* __restrict__ logits){
  const int lane = threadIdx.x & 63, w = threadIdx.x >> 6;
  const int cl = lane & 15, ko = (lane >> 4)*8;
  const size_t m0 = ((size_t)blockIdx.x*4 + w)*16;
  const u16* ap = outs + (m0+cl)*1024 + ko;
  f32x4 acc[3];
  #pragma unroll
  for (int nt=0; nt<3; ++nt) acc[nt] = (f32x4){0.f,0.f,0.f,0.f};
  const u16* bp = Wdec + (size_t)cl*1024 + ko;
  for (int k0=0; k0<1024; k0+=32){
    bf16x8 a = *(const bf16x8*)(ap + k0);
    #pragma unroll
    for (int nt=0; nt<3; ++nt){
      bf16x8 b = *(const bf16x8*)(bp + (size_t)nt*16*1024 + k0);
      acc[nt] = MFMA16(a, b, acc[nt]);
    }
  }
  const int rbase = (lane >> 4)*4;
  #pragma unroll
  for (int nt=0; nt<3; ++nt){
    #pragma unroll
    for (int q=0; q<4; ++q){
      int v = nt*16 + cl;
      if (v < 47){
        size_t row = m0 + rbase + q;   // row = t*256 + b
        int tt = (int)(row >> 8);
        int b  = (int)(row & 255);
        logits[((size_t)b*99 + tt)*47 + v] = acc[nt][q] + bdec[v];
      }
    }
  }
}

// ---- final hT / cT copy-out (t=98: hist slots 98&7=2, outsbF slot 99)
__global__ void k_final(const u16* __restrict__ h0s, const u16* __restrict__ h1s,
                        const u16* __restrict__ h2s, const float* __restrict__ cst,
                        float* __restrict__ out){
  long i = (long)blockIdx.x*256 + threadIdx.x;
  if (i < (long)3*BH){
    int l = (int)(i >> 18); long r = i & (BH-1);
    const u16* src = (l==0) ? h0s : (l==1) ? h1s : h2s;
    out[1191168 + i] = bf2f(src[r]);
    out[1191168 + 786432 + i] = cst[i];
  }
}

extern "C" void kernel_launch(void* const* d_in, const int* in_sizes, int n_in,
                              void* d_out, int out_size, void* d_ws, size_t ws_size,
                              hipStream_t stream) {
  (void)in_sizes; (void)n_in; (void)out_size; (void)ws_size;
  const int*   x      = (const int*)  d_in[0];
  const float* props  = (const float*)d_in[1];
  const float* h0     = (const float*)d_in[2];
  const float* c0     = (const float*)d_in[3];
  const float* E      = (const float*)d_in[4];
  const float* W_ih0  = (const float*)d_in[5];
  const float* W_hh0  = (const float*)d_in[6];
  const float* b_ih0  = (const float*)d_in[7];
  const float* b_hh0  = (const float*)d_in[8];
  const float* W_ih_r = (const float*)d_in[9];
  const float* W_hh_r = (const float*)d_in[10];
  const float* b_ih_r = (const float*)d_in[11];
  const float* b_hh_r = (const float*)d_in[12];
  const float* W_dec  = (const float*)d_in[13];
  const float* b_dec  = (const float*)d_in[14];
  float* out = (float*)d_out;

  // workspace layout (~130 MB)
  u16* WpkH   = (u16*)d_ws;                 // 3 x 4,194,304 (W_hh stream blocks)
  u16* WpkI   = WpkH  + (size_t)12582912;   // 2 x 4,194,304 (W_ih_r stream blocks)
  u16* Wdec   = WpkI  + (size_t)8388608;    // 48*1024 (row 47 = 0)
  u16* Ebf    = Wdec  + (size_t)49152;      // 48*1024 (row 47 = 0)
  u16* hist0  = Ebf   + (size_t)49152;      // 8 x BH  (h0 ring; slot 7 = init)
  u16* hist1  = hist0 + (size_t)8*BH;       // 8 x BH
  u16* outsbF = hist1 + (size_t)8*BH;       // 100 x BH (slot 0 = h2 init; t -> t+1)
  u16* xpb1   = outsbF + (size_t)100*BH;    // [2 win-parity][2 tsub][256][4096]
  u16* xpb2   = xpb1  + (size_t)4194304;    // same
  u16* Wih0b  = xpb1;                       // ALIAS: prep-only, dead before xp writes
  float* gxe   = (float*)(xpb2 + (size_t)4194304); // 48*4096
  float* gxp   = gxe   + (size_t)196608;           // 256*4096
  float* bias0 = gxp   + (size_t)1048576;          // 4096
  float* bcat  = bias0 + 4096;                     // 2*4096
  float* cst   = bcat  + 8192;                     // 3 x BH f32

  // ---- prep
  k_repackB<<<2048, 256, 0, stream>>>(W_hh0, W_hh0, WpkH, 16);
  k_repackB<<<2048, 256, 0, stream>>>(W_hh_r, W_hh_r, WpkH + (size_t)4194304, 16);
  k_repackB<<<2048, 256, 0, stream>>>(W_hh_r + (size_t)4194304, W_hh_r + (size_t)4194304,
                                      WpkH + (size_t)8388608, 16);
  k_repackB<<<2048, 256, 0, stream>>>(W_ih_r, W_ih_r, WpkI, 16);
  k_repackB<<<2048, 256, 0, stream>>>(W_ih_r + (size_t)4194304, W_ih_r + (size_t)4194304,
                                      WpkI + (size_t)4194304, 16);
  k_conv<<<2048, 256, 0, stream>>>(W_ih0, Wih0b, (long)4096*1024, 1024, 1027, 1024, 0);
  k_conv<<<24,   256, 0, stream>>>(E,     Ebf,   (long)47*1024,   1024, 1024, 1024, 0);
  k_conv<<<24,   256, 0, stream>>>(W_dec, Wdec,  (long)47*1024,   1024, 1024, 1024, 0);
  k_misc<<<7221, 256, 0, stream>>>(b_ih0, b_hh0, b_ih_r, b_hh_r, h0, c0, props, W_ih0,
                                   Ebf, Wdec, bias0, bcat, hist0, hist1, outsbF, cst, gxp);
  k_gxemb<<<dim3(3,256), 64, 0, stream>>>(Ebf, Wih0b, gxe);

  // ---- merged recurrence: d runs (L0@d, L1@d-3, L2@d-6) + one xp window
  (void)hipFuncSetAttribute(reinterpret_cast<const void*>(k_diag),
                            hipFuncAttributeMaxDynamicSharedMemorySize, 73728);
  for (int d = 0; d <= 104; ++d){
    bool hx = ((d & 1) == 0) ? (d >= 2 && d <= 100) : (d >= 5 && d <= 103);
    k_diag<<<384 + (hx ? 256 : 0), 256, 73728, stream>>>(
        d, x, hist0, hist1, outsbF, cst, WpkH, WpkI,
        bias0, bcat, gxe, gxp, xpb1, xpb2);
  }

  // ---- decode + final states
  k_decode<<<396, 256, 0, stream>>>(outsbF + (size_t)BH, Wdec, b_dec, out);
  k_final<<<3072, 256, 0, stream>>>(hist0 + (size_t)2*BH, hist1 + (size_t)2*BH,
                                    outsbF + (size_t)99*BH, cst, out);
}